// Round 1
// baseline (36.567 us; speedup 1.0000x reference)
//
#include <hip/hip_runtime.h>

// Conv4D with separable kernel k4 = K (3x3) ⊗ K (3x3).
// input: (8192, 8,8,8,8) fp32 ; output: (8192, 6,6,6,6) fp32
// Stage 1: conv over last two dims -> t (8,8,6,6)
// Stage 2: conv over first two dims -> out (6,6,6,6)

#define N_SAMPLES 8192
#define IN_PER    4096   // 8*8*8*8
#define T_PER     2304   // 8*8*6*6
#define OUT_PER   1296   // 6*6*6*6

__global__ __launch_bounds__(256)
void Conv4D_kernel(const float* __restrict__ in,
                   const float* __restrict__ kern,
                   float* __restrict__ out)
{
    __shared__ float x[IN_PER];   // 16 KB
    __shared__ float t[T_PER];    // 9.2 KB, layout [a*8+b][6][6]

    const int n   = blockIdx.x;
    const int tid = threadIdx.x;

    // 3x3 kernel taps into registers (uniform broadcast loads)
    float K[9];
#pragma unroll
    for (int i = 0; i < 9; ++i) K[i] = kern[i];

    // --- cooperative load: 4096 floats = 1024 float4, coalesced ---
    const float4* src = reinterpret_cast<const float4*>(in + (size_t)n * IN_PER);
    float4* xv = reinterpret_cast<float4*>(x);
#pragma unroll
    for (int q = 0; q < 4; ++q)
        xv[tid + 256 * q] = src[tid + 256 * q];
    __syncthreads();

    // --- stage 1: t[ab][c][d] = sum_{k,l} x[ab][c+k][d+l] * K[k][l] ---
    // 2304 elements / 256 threads = exactly 9 per thread
#pragma unroll
    for (int s = 0; s < 9; ++s) {
        const int e  = tid + 256 * s;
        const int d  = e % 6;
        const int r  = e / 6;
        const int c  = r % 6;
        const int ab = r / 6;               // 0..63 == a*8+b
        const float* xp = x + ab * 64 + c * 8 + d;
        float acc = 0.f;
#pragma unroll
        for (int k = 0; k < 3; ++k)
#pragma unroll
            for (int l = 0; l < 3; ++l)
                acc = fmaf(xp[k * 8 + l], K[k * 3 + l], acc);
        t[e] = acc;
    }
    __syncthreads();

    // --- stage 2: out[a][b][c][d] = sum_{i,j} t[(a+i)*8+(b+j)][c][d] * K[i][j] ---
    float* dst = out + (size_t)n * OUT_PER;
    for (int o = tid; o < OUT_PER; o += 256) {
        const int d  = o % 6;
        const int r  = o / 6;
        const int c  = r % 6;
        const int r2 = r / 6;
        const int b  = r2 % 6;
        const int a  = r2 / 6;
        float acc = 0.f;
#pragma unroll
        for (int i = 0; i < 3; ++i)
#pragma unroll
            for (int j = 0; j < 3; ++j)
                acc = fmaf(t[((a + i) * 8 + (b + j)) * 36 + c * 6 + d],
                           K[i * 3 + j], acc);
        dst[o] = acc;
    }
}

extern "C" void kernel_launch(void* const* d_in, const int* in_sizes, int n_in,
                              void* d_out, int out_size, void* d_ws, size_t ws_size,
                              hipStream_t stream) {
    const float* in   = (const float*)d_in[0];
    const float* kern = (const float*)d_in[1];
    float* out        = (float*)d_out;

    Conv4D_kernel<<<N_SAMPLES, 256, 0, stream>>>(in, kern, out);
}